// Round 9
// baseline (997.232 us; speedup 1.0000x reference)
//
#include <hip/hip_runtime.h>
#include <hip/hip_bf16.h>
#include <stdint.h>

typedef __attribute__((ext_vector_type(8))) short bf16x8;
typedef __attribute__((ext_vector_type(4))) float f32x4;

static __device__ __forceinline__ unsigned short f2bf(float f) {
  union { float f; unsigned int u; } v; v.f = f;
  unsigned int u = v.u;
  u += 0x7FFFu + ((u >> 16) & 1u);   // RNE
  return (unsigned short)(u >> 16);
}
static __device__ __forceinline__ float bf2f(unsigned short h) {
  union { unsigned int u; float f; } v; v.u = ((unsigned int)h) << 16; return v.f;
}

typedef __attribute__((address_space(1))) void gvoid;
typedef __attribute__((address_space(3))) void lvoid;
static __device__ __forceinline__ void gload_lds16(const void* gp, void* lp) {
  __builtin_amdgcn_global_load_lds((gvoid*)gp, (lvoid*)lp, 16, 0, 0);
}

// ---------------- X fp32 -> Xb bf16 ----------------
__global__ __launch_bounds__(256) void k_convX(const float* __restrict__ X,
                                               unsigned short* __restrict__ Xb) {
  size_t i = ((size_t)blockIdx.x * 256 + threadIdx.x) * 8;
  const size_t stride = (size_t)4096 * 256 * 8;
  for (; i < (size_t)16777216; i += stride) {
    float4 v0 = *(const float4*)(X + i), v1 = *(const float4*)(X + i + 4);
    unsigned short h[8];
    h[0]=f2bf(v0.x); h[1]=f2bf(v0.y); h[2]=f2bf(v0.z); h[3]=f2bf(v0.w);
    h[4]=f2bf(v1.x); h[5]=f2bf(v1.y); h[6]=f2bf(v1.z); h[7]=f2bf(v1.w);
    *(uint4*)(Xb + i) = *(uint4*)h;
  }
}

// ---------------- W [K][N] fp32 -> Wt [N][K] bf16 ----------------
__global__ __launch_bounds__(256) void k_convW(const float* __restrict__ W,
                                               unsigned short* __restrict__ Wt) {
  __shared__ __align__(16) unsigned short lds[64][72];
  const int tid = threadIdx.x;
  const int n0 = blockIdx.x * 64, k0 = blockIdx.y * 64;
  for (int i = 0; i < 4; ++i) {
    int c = i * 256 + tid;
    int r = c >> 4, c4 = (c & 15) * 4;
    float4 v = *(const float4*)(W + (size_t)(k0 + r) * 1024 + n0 + c4);
    unsigned short* p = &lds[r][c4];
    p[0] = f2bf(v.x); p[1] = f2bf(v.y); p[2] = f2bf(v.z); p[3] = f2bf(v.w);
  }
  __syncthreads();
  for (int i = 0; i < 2; ++i) {
    int c = i * 256 + tid;
    int n = c >> 3, k8 = (c & 7) * 8;
    unsigned short tmp[8];
    for (int j = 0; j < 8; ++j) tmp[j] = lds[k8 + j][n];
    *(uint4*)(Wt + (size_t)(n0 + n) * 1024 + k0 + k8) = *(uint4*)tmp;
  }
}

// ===================== bf16 core (256x256, BK=32, ring4) =====================
template<int NT>
__device__ __forceinline__ void gemm_core(
    const unsigned short* __restrict__ Ag, int lda, int ar0,
    const unsigned short* __restrict__ Bg, int ldb, int br0,
    unsigned short* __restrict__ As, unsigned short* __restrict__ Bs,
    f32x4 (&acc)[8][4]) {
  const int tid = threadIdx.x, lane = tid & 63, wid = tid >> 6;
  const int wr = wid >> 2, wc = wid & 3;
  const int rl = lane & 15;
  const int rslot = (((lane >> 4) ^ (lane & 3) ^ ((lane >> 2) & 3))) * 8;
  const int q = tid >> 2;
  const int sslot = (((tid & 3) ^ (q & 3) ^ ((q >> 2) & 3))) * 8;

#define STAGE_T(dstbase, src, ld, r0, kt)                                      \
  _Pragma("unroll")                                                            \
  for (int r_ = 0; r_ < 2; ++r_)                                               \
    gload_lds16((src) + (size_t)((r0) + r_ * 128 + q) * (ld) + (kt) * 32 + sslot, \
                (char*)(dstbase) + r_ * 8192 + wid * 1024);

  STAGE_T(As + 0 * 8192, Ag, lda, ar0, 0)
  STAGE_T(Bs + 0 * 8192, Bg, ldb, br0, 0)
  STAGE_T(As + 1 * 8192, Ag, lda, ar0, 1)
  STAGE_T(Bs + 1 * 8192, Bg, ldb, br0, 1)
  STAGE_T(As + 2 * 8192, Ag, lda, ar0, 2)
  STAGE_T(Bs + 2 * 8192, Bg, ldb, br0, 2)
  asm volatile("s_waitcnt vmcnt(8)" ::: "memory");
  __builtin_amdgcn_s_barrier();

  bf16x8 a[4], b[4], a2[4];
  for (int t = 0; t < NT; ++t) {
    const int sl = t & 3;
    const int ps = (t + 3 < NT) ? (t + 3) : (NT - 1);
    const int psl = (t + 3) & 3;
    const unsigned short* Ab = As + sl * 8192;
    const unsigned short* Bb = Bs + sl * 8192;
#pragma unroll
    for (int m = 0; m < 4; ++m)
      a[m] = *(const bf16x8*)(Ab + (wr * 128 + m * 16 + rl) * 32 + rslot);
#pragma unroll
    for (int n = 0; n < 4; ++n)
      b[n] = *(const bf16x8*)(Bb + (wc * 64 + n * 16 + rl) * 32 + rslot);
    STAGE_T(As + psl * 8192, Ag, lda, ar0, ps)
    __builtin_amdgcn_s_barrier();
    asm volatile("s_waitcnt lgkmcnt(0)" ::: "memory");
    __builtin_amdgcn_s_setprio(1);
#pragma unroll
    for (int m = 0; m < 4; ++m)
#pragma unroll
      for (int n = 0; n < 4; ++n)
        acc[m][n] = __builtin_amdgcn_mfma_f32_16x16x32_bf16(a[m], b[n], acc[m][n], 0, 0, 0);
    __builtin_amdgcn_s_setprio(0);
    __builtin_amdgcn_s_barrier();
#pragma unroll
    for (int m = 0; m < 4; ++m)
      a2[m] = *(const bf16x8*)(Ab + (wr * 128 + (m + 4) * 16 + rl) * 32 + rslot);
    STAGE_T(Bs + psl * 8192, Bg, ldb, br0, ps)
    __builtin_amdgcn_s_barrier();
    asm volatile("s_waitcnt lgkmcnt(0)" ::: "memory");
    __builtin_amdgcn_s_setprio(1);
#pragma unroll
    for (int m = 0; m < 4; ++m)
#pragma unroll
      for (int n = 0; n < 4; ++n)
        acc[m + 4][n] = __builtin_amdgcn_mfma_f32_16x16x32_bf16(a2[m], b[n], acc[m + 4][n], 0, 0, 0);
    __builtin_amdgcn_s_setprio(0);
    asm volatile("s_waitcnt vmcnt(8)" ::: "memory");
    __builtin_amdgcn_s_barrier();
  }
  asm volatile("s_waitcnt vmcnt(0)" ::: "memory");
#undef STAGE_T
}

// ------- GEMM1: F(bf16) + Ft(bf16, transposed) = Xb @ Wt^T + bias -------
__global__ __launch_bounds__(512, 2) void k_gemm1(const unsigned short* __restrict__ Xb,
                                                  const unsigned short* __restrict__ Wt,
                                                  const float* __restrict__ bias,
                                                  unsigned short* __restrict__ F,
                                                  unsigned short* __restrict__ Ft) {
  __shared__ __align__(16) unsigned short As[4 * 8192];
  __shared__ __align__(16) unsigned short Bs[4 * 8192];
  const int bid = blockIdx.x;                      // nwg = 256
  const int swz = (bid & 7) * 32 + (bid >> 3);
  const int m0 = (swz >> 2) * 256, n0 = (swz & 3) * 256;
  f32x4 acc[8][4] = {};
  gemm_core<32>(Xb, 1024, m0, Wt, 1024, n0, As, Bs, acc);
  const int tid = threadIdx.x, lane = tid & 63, wid = tid >> 6;
  const int wr = wid >> 2, wc = wid & 3;
  const int r4 = (lane >> 4) * 4, cl = lane & 15;
#pragma unroll
  for (int n = 0; n < 4; ++n) {
    int col = n0 + wc * 64 + n * 16 + cl;
    float bv = bias[col];
#pragma unroll
    for (int m = 0; m < 8; ++m) {
      int row = m0 + wr * 128 + m * 16 + r4;
      __align__(8) unsigned short hh[4];
#pragma unroll
      for (int j = 0; j < 4; ++j) hh[j] = f2bf(acc[m][n][j] + bv);
#pragma unroll
      for (int j = 0; j < 4; ++j) F[(size_t)(row + j) * 1024 + col] = hh[j];
      const int z = row >> 11, s = row & 2047;
      *(uint2*)(Ft + ((size_t)z * 1024 + col) * 2048 + s) = *(const uint2*)hh;
    }
  }
}

// ------- GEMM2: E[b] = bf16(F F^T + distbias); 256x128 tile, dbuf, 3 blk/CU -------
__global__ __launch_bounds__(512, 6) void k_gemm2(const unsigned short* __restrict__ F,
                                                  unsigned short* __restrict__ E) {
  __shared__ __align__(16) unsigned short As2[2][8192];  // 2 x 256x32 bf16 = 2x16KB
  __shared__ __align__(16) unsigned short Bs2[2][4096];  // 2 x 128x32 bf16 = 2x8KB
  const int bid = blockIdx.x;                      // nwg = 1024
  const int swz = (bid & 7) * 128 + (bid >> 3);    // one batch per XCD
  const int z = swz >> 7;
  const int m0 = ((swz >> 4) & 7) * 256, n0 = (swz & 15) * 128;
  const unsigned short* Fb = F + (size_t)z * 2048 * 1024;
  unsigned short* Eb = E + (size_t)z * 2048 * 2048;
  const int tid = threadIdx.x, lane = tid & 63, wid = tid >> 6;
  const int wr = wid >> 2, wc = wid & 3;
  const int rl = lane & 15;
  const int rslot = ((lane >> 4) ^ (lane & 3) ^ ((lane >> 2) & 3)) * 8;
  const int q = tid >> 2;
  const int sslot = ((tid & 3) ^ (q & 3) ^ ((q >> 2) & 3)) * 8;
  f32x4 acc[8][2] = {};

#define STAGE_A2(buf, kt)                                                      \
  _Pragma("unroll")                                                            \
  for (int r_ = 0; r_ < 2; ++r_)                                               \
    gload_lds16(Fb + (size_t)(m0 + r_ * 128 + q) * 1024 + (kt) * 32 + sslot,   \
                (char*)(As2[buf]) + r_ * 8192 + wid * 1024);
#define STAGE_B2(buf, kt)                                                      \
  gload_lds16(Fb + (size_t)(n0 + q) * 1024 + (kt) * 32 + sslot,                \
              (char*)(Bs2[buf]) + wid * 1024);

  STAGE_A2(0, 0)
  STAGE_B2(0, 0)
  asm volatile("s_waitcnt vmcnt(0)" ::: "memory");
  __builtin_amdgcn_s_barrier();

  for (int t = 0; t < 32; ++t) {
    const int cur = t & 1;
    bf16x8 a[8], b[2];
#pragma unroll
    for (int m = 0; m < 8; ++m)
      a[m] = *(const bf16x8*)(&As2[cur][(wr * 128 + m * 16 + rl) * 32 + rslot]);
#pragma unroll
    for (int n = 0; n < 2; ++n)
      b[n] = *(const bf16x8*)(&Bs2[cur][(wc * 32 + n * 16 + rl) * 32 + rslot]);
    if (t < 31) { STAGE_A2(cur ^ 1, t + 1) STAGE_B2(cur ^ 1, t + 1) }
    asm volatile("s_waitcnt lgkmcnt(0)" ::: "memory");
    __builtin_amdgcn_s_setprio(1);
#pragma unroll
    for (int m = 0; m < 8; ++m)
#pragma unroll
      for (int n = 0; n < 2; ++n)
        acc[m][n] = __builtin_amdgcn_mfma_f32_16x16x32_bf16(a[m], b[n], acc[m][n], 0, 0, 0);
    __builtin_amdgcn_s_setprio(0);
    if (t < 31) asm volatile("s_waitcnt vmcnt(0)" ::: "memory");
    __builtin_amdgcn_s_barrier();
  }
#undef STAGE_A2
#undef STAGE_B2

  const int r4 = (lane >> 4) * 4, cl = lane & 15;
#pragma unroll
  for (int m = 0; m < 8; ++m) {
    int row = m0 + wr * 128 + m * 16 + r4;
#pragma unroll
    for (int n = 0; n < 2; ++n) {
      int col = n0 + wc * 32 + n * 16 + cl;
#pragma unroll
      for (int j = 0; j < 4; ++j) {
        int rr = row + j;
        int d = rr - col; d = d < 0 ? -d : d; d = d > 10 ? 10 : d;
        Eb[(size_t)rr * 2048 + col] = f2bf(acc[m][n][j] + (float)d * 0.01f);
      }
    }
  }
}

// ---------------- row softmax, wave-per-row, bf16 in place ----------------
__global__ __launch_bounds__(256) void k_softmax(unsigned short* __restrict__ E) {
  const int tid = threadIdx.x, lane = tid & 63, w = tid >> 6;
  unsigned short* row = E + ((size_t)blockIdx.x * 4 + w) * 2048;
  uint4 v[4];
  float f[32];
#pragma unroll
  for (int i = 0; i < 4; ++i) {
    v[i] = ((const uint4*)row)[i * 64 + lane];
    const unsigned int* up = (const unsigned int*)&v[i];
#pragma unroll
    for (int k = 0; k < 4; ++k) {
      f[i * 8 + 2 * k]     = bf2f((unsigned short)(up[k] & 0xFFFF));
      f[i * 8 + 2 * k + 1] = bf2f((unsigned short)(up[k] >> 16));
    }
  }
  float mx = f[0];
#pragma unroll
  for (int i = 1; i < 32; ++i) mx = fmaxf(mx, f[i]);
  for (int s = 32; s > 0; s >>= 1) mx = fmaxf(mx, __shfl_xor(mx, s));
  float sum = 0.f;
#pragma unroll
  for (int i = 0; i < 32; ++i) { f[i] = __expf(f[i] - mx); sum += f[i]; }
  for (int s = 32; s > 0; s >>= 1) sum += __shfl_xor(sum, s);
  const float inv = 1.0f / sum;
#pragma unroll
  for (int i = 0; i < 4; ++i) {
    unsigned short hh[8];
#pragma unroll
    for (int k = 0; k < 8; ++k) hh[k] = f2bf(f[i * 8 + k] * inv);
    ((uint4*)row)[i * 64 + lane] = *(uint4*)hh;
  }
}

// ---------------- GEMM3: out[b] = P @ F (B = Ft), fp32 out ----------------
__global__ __launch_bounds__(512, 2) void k_gemm3(const unsigned short* __restrict__ P,
                                                  const unsigned short* __restrict__ Ft,
                                                  float* __restrict__ out) {
  __shared__ __align__(16) unsigned short As[4 * 8192];
  __shared__ __align__(16) unsigned short Bs[4 * 8192];
  const int bid = blockIdx.x;                      // nwg = 256
  const int swz = (bid & 7) * 32 + (bid >> 3);     // one batch per XCD
  const int z = swz >> 5;
  const int m0 = ((swz >> 2) & 7) * 256, n0 = (swz & 3) * 256;
  const unsigned short* Pb = P + (size_t)z * 2048 * 2048;
  const unsigned short* Ftb = Ft + (size_t)z * 1024 * 2048;
  float* outb = out + (size_t)z * 2048 * 1024;
  f32x4 acc[8][4] = {};
  gemm_core<64>(Pb, 2048, m0, Ftb, 2048, n0, As, Bs, acc);
  const int tid = threadIdx.x, lane = tid & 63, wid = tid >> 6;
  const int wr = wid >> 2, wc = wid & 3;
  const int r4 = (lane >> 4) * 4, cl = lane & 15;
#pragma unroll
  for (int m = 0; m < 8; ++m) {
    int row = m0 + wr * 128 + m * 16 + r4;
#pragma unroll
    for (int n = 0; n < 4; ++n) {
      int col = n0 + wc * 64 + n * 16 + cl;
#pragma unroll
      for (int j = 0; j < 4; ++j)
        outb[(size_t)(row + j) * 1024 + col] = acc[m][n][j];
    }
  }
}

extern "C" void kernel_launch(void* const* d_in, const int* in_sizes, int n_in,
                              void* d_out, int out_size, void* d_ws, size_t ws_size,
                              hipStream_t stream) {
  const float* x = (const float*)d_in[0];
  const float* W = (const float*)d_in[1];
  const float* b = (const float*)d_in[2];
  float* out = (float*)d_out;

  // ws: Wt 2MB | F 32MB | Ft 32MB | E(bf16) 64MB | Xb 32MB
  unsigned short* Wt = (unsigned short*)d_ws;
  unsigned short* F  = (unsigned short*)((char*)d_ws + (2ull   << 20));
  unsigned short* Ft = (unsigned short*)((char*)d_ws + (34ull  << 20));
  unsigned short* E  = (unsigned short*)((char*)d_ws + (66ull  << 20));
  unsigned short* Xb = (unsigned short*)((char*)d_ws + (130ull << 20));

  k_convW  <<<dim3(16, 16), 256, 0, stream>>>(W, Wt);
  k_convX  <<<dim3(4096),   256, 0, stream>>>(x, Xb);
  k_gemm1  <<<dim3(256),    512, 0, stream>>>(Xb, Wt, b, F, Ft);
  k_gemm2  <<<dim3(1024),   512, 0, stream>>>(F, E);
  k_softmax<<<dim3(4096),   256, 0, stream>>>(E);
  k_gemm3  <<<dim3(256),    512, 0, stream>>>(E, Ft, out);
}